// Round 1
// baseline (530.384 us; speedup 1.0000x reference)
//
#include <hip/hip_runtime.h>
#include <math.h>

// Problem constants: B=2, L=256, H=512, NH=8, DH=64
// ws layout (floats): q[262144] k[262144] val[262144] g[2097152] scores[1048576] ctx[262144]
// total = 16 MB

// ---------------------------------------------------------------------------
// GEMM: C[512,512] = A[512,512] @ W[512,512] + bias[512]; grid z selects 1 of 3
// BM=BN=64, BK=16, 256 threads, 4x4 micro-tile per thread.
// ---------------------------------------------------------------------------
__global__ __launch_bounds__(256) void gemm512_k(
    const float* __restrict__ A0, const float* __restrict__ W0,
    const float* __restrict__ b0, float* __restrict__ C0,
    const float* __restrict__ A1, const float* __restrict__ W1,
    const float* __restrict__ b1, float* __restrict__ C1,
    const float* __restrict__ A2, const float* __restrict__ W2,
    const float* __restrict__ b2, float* __restrict__ C2) {
  const int z = blockIdx.z;
  const float* A    = (z == 0) ? A0 : (z == 1) ? A1 : A2;
  const float* W    = (z == 0) ? W0 : (z == 1) ? W1 : W2;
  const float* bias = (z == 0) ? b0 : (z == 1) ? b1 : b2;
  float* C          = (z == 0) ? C0 : (z == 1) ? C1 : C2;

  __shared__ float As[16][64];  // [k][m] (A transposed for b128 reads)
  __shared__ float Bs[16][64];  // [k][n]
  const int t  = threadIdx.x;
  const int tx = t & 15, ty = t >> 4;
  const int bm0 = blockIdx.y * 64, bn0 = blockIdx.x * 64;
  const int lm  = t >> 2;          // A-stage row 0..63
  const int lkq = (t & 3) << 2;    // A-stage k quad
  const int lk  = t >> 4;          // B-stage k 0..15
  const int lnq = (t & 15) << 2;   // B-stage n quad

  float acc[4][4] = {};
  for (int kt = 0; kt < 32; ++kt) {
    float4 a4 = *(const float4*)&A[(bm0 + lm) * 512 + kt * 16 + lkq];
    float4 b4 = *(const float4*)&W[(kt * 16 + lk) * 512 + bn0 + lnq];
    As[lkq + 0][lm] = a4.x;
    As[lkq + 1][lm] = a4.y;
    As[lkq + 2][lm] = a4.z;
    As[lkq + 3][lm] = a4.w;
    *(float4*)&Bs[lk][lnq] = b4;
    __syncthreads();
#pragma unroll
    for (int k = 0; k < 16; ++k) {
      float4 av = *(const float4*)&As[k][ty * 4];
      float4 bv = *(const float4*)&Bs[k][tx * 4];
      acc[0][0] = fmaf(av.x, bv.x, acc[0][0]);
      acc[0][1] = fmaf(av.x, bv.y, acc[0][1]);
      acc[0][2] = fmaf(av.x, bv.z, acc[0][2]);
      acc[0][3] = fmaf(av.x, bv.w, acc[0][3]);
      acc[1][0] = fmaf(av.y, bv.x, acc[1][0]);
      acc[1][1] = fmaf(av.y, bv.y, acc[1][1]);
      acc[1][2] = fmaf(av.y, bv.z, acc[1][2]);
      acc[1][3] = fmaf(av.y, bv.w, acc[1][3]);
      acc[2][0] = fmaf(av.z, bv.x, acc[2][0]);
      acc[2][1] = fmaf(av.z, bv.y, acc[2][1]);
      acc[2][2] = fmaf(av.z, bv.z, acc[2][2]);
      acc[2][3] = fmaf(av.z, bv.w, acc[2][3]);
      acc[3][0] = fmaf(av.w, bv.x, acc[3][0]);
      acc[3][1] = fmaf(av.w, bv.y, acc[3][1]);
      acc[3][2] = fmaf(av.w, bv.z, acc[3][2]);
      acc[3][3] = fmaf(av.w, bv.w, acc[3][3]);
    }
    __syncthreads();
  }
  float4 bb = *(const float4*)&bias[bn0 + tx * 4];
#pragma unroll
  for (int r = 0; r < 4; ++r) {
    float4 o;
    o.x = acc[r][0] + bb.x;
    o.y = acc[r][1] + bb.y;
    o.z = acc[r][2] + bb.z;
    o.w = acc[r][3] + bb.w;
    *(float4*)&C[(size_t)(bm0 + ty * 4 + r) * 512 + bn0 + tx * 4] = o;
  }
}

// ---------------------------------------------------------------------------
// g[b,i,n,e] = sum_d Wr[e, n*64+d] * (q[b,i,n*64+d] + v[n,d])
// grid: (bi_tile=8, e_tile=8, n=8); K=64 fully staged.
// ---------------------------------------------------------------------------
__global__ __launch_bounds__(256) void g_gemm_k(const float* __restrict__ q,
                                                const float* __restrict__ vbias,
                                                const float* __restrict__ Wr,
                                                float* __restrict__ g) {
  __shared__ float As[64][64];  // [d][m]  qv
  __shared__ float Bs[64][64];  // [d][e]  Wr^T slice
  const int t   = threadIdx.x;
  const int bi0 = blockIdx.x * 64;
  const int eb  = blockIdx.y * 64;
  const int n   = blockIdx.z;
  const int row = t >> 2;        // 0..63
  const int dq  = (t & 3) << 4;  // 0,16,32,48
#pragma unroll
  for (int s = 0; s < 4; ++s) {
    int d = dq + s * 4;
    float4 a4 = *(const float4*)&q[(size_t)(bi0 + row) * 512 + n * 64 + d];
    float4 v4 = *(const float4*)&vbias[n * 64 + d];
    As[d + 0][row] = a4.x + v4.x;
    As[d + 1][row] = a4.y + v4.y;
    As[d + 2][row] = a4.z + v4.z;
    As[d + 3][row] = a4.w + v4.w;
    float4 b4 = *(const float4*)&Wr[(size_t)(eb + row) * 512 + n * 64 + d];
    Bs[d + 0][row] = b4.x;
    Bs[d + 1][row] = b4.y;
    Bs[d + 2][row] = b4.z;
    Bs[d + 3][row] = b4.w;
  }
  __syncthreads();
  const int tx = t & 15, ty = t >> 4;
  float acc[4][4] = {};
#pragma unroll 8
  for (int d = 0; d < 64; ++d) {
    float4 av = *(const float4*)&As[d][ty * 4];
    float4 bv = *(const float4*)&Bs[d][tx * 4];
    acc[0][0] = fmaf(av.x, bv.x, acc[0][0]);
    acc[0][1] = fmaf(av.x, bv.y, acc[0][1]);
    acc[0][2] = fmaf(av.x, bv.z, acc[0][2]);
    acc[0][3] = fmaf(av.x, bv.w, acc[0][3]);
    acc[1][0] = fmaf(av.y, bv.x, acc[1][0]);
    acc[1][1] = fmaf(av.y, bv.y, acc[1][1]);
    acc[1][2] = fmaf(av.y, bv.z, acc[1][2]);
    acc[1][3] = fmaf(av.y, bv.w, acc[1][3]);
    acc[2][0] = fmaf(av.z, bv.x, acc[2][0]);
    acc[2][1] = fmaf(av.z, bv.y, acc[2][1]);
    acc[2][2] = fmaf(av.z, bv.z, acc[2][2]);
    acc[2][3] = fmaf(av.z, bv.w, acc[2][3]);
    acc[3][0] = fmaf(av.w, bv.x, acc[3][0]);
    acc[3][1] = fmaf(av.w, bv.y, acc[3][1]);
    acc[3][2] = fmaf(av.w, bv.z, acc[3][2]);
    acc[3][3] = fmaf(av.w, bv.w, acc[3][3]);
  }
#pragma unroll
  for (int r = 0; r < 4; ++r) {
    float4 o = {acc[r][0], acc[r][1], acc[r][2], acc[r][3]};
    *(float4*)&g[((size_t)(bi0 + ty * 4 + r) * 8 + n) * 512 + eb + tx * 4] = o;
  }
}

// ---------------------------------------------------------------------------
// scores[b,n,i,j] = ((qu.k) + (rpe.g) + (br.qv)) / 8, masked to -1e15 for
// j >= seq_len[b]+lex_num. One block per (b,i, j-half); wave w owns 32 j's;
// lane l owns e-slice [8l, 8l+8).
// ---------------------------------------------------------------------------
__global__ __launch_bounds__(256) void score_k(
    const float* __restrict__ q, const float* __restrict__ kk,
    const float* __restrict__ g, const float* __restrict__ rpe,
    const float* __restrict__ u, const float* __restrict__ v,
    const float* __restrict__ br, const int* __restrict__ seq_len,
    const int* __restrict__ lex_num, float* __restrict__ scores) {
  const int bi = blockIdx.x;
  const int b = bi >> 8, i = bi & 255;
  const int lane = threadIdx.x & 63;
  const int w = threadIdx.x >> 6;
  const int grp = lane >> 3, sub = lane & 7;
  const int e0 = lane << 3;
  const int jblock = blockIdx.y * 128;
  const int jbase = jblock + w * 32;
  __shared__ float ac[8][128];
  __shared__ float cterm[8];
  const int limit = seq_len[b] + lex_num[0];

  // per-lane qu slice
  float qu[8];
  {
    const float* qrow = q + (size_t)bi * 512 + e0;
    float4 q0 = *(const float4*)qrow;
    float4 q1 = *(const float4*)(qrow + 4);
    float4 u0 = *(const float4*)(u + e0);
    float4 u1 = *(const float4*)(u + e0 + 4);
    qu[0] = q0.x + u0.x; qu[1] = q0.y + u0.y; qu[2] = q0.z + u0.z; qu[3] = q0.w + u0.w;
    qu[4] = q1.x + u1.x; qu[5] = q1.y + u1.y; qu[6] = q1.z + u1.z; qu[7] = q1.w + u1.w;
  }
  // phase 1: AC (head = grp since lane's 8 e's lie inside head lane/8)
  for (int jj = 0; jj < 32; ++jj) {
    int j = jbase + jj;
    const float* krow = kk + (size_t)(b * 256 + j) * 512 + e0;
    float4 k0 = *(const float4*)krow;
    float4 k1 = *(const float4*)(krow + 4);
    float p = qu[0] * k0.x;
    p = fmaf(qu[1], k0.y, p);
    p = fmaf(qu[2], k0.z, p);
    p = fmaf(qu[3], k0.w, p);
    p = fmaf(qu[4], k1.x, p);
    p = fmaf(qu[5], k1.y, p);
    p = fmaf(qu[6], k1.z, p);
    p = fmaf(qu[7], k1.w, p);
    p += __shfl_xor(p, 1);
    p += __shfl_xor(p, 2);
    p += __shfl_xor(p, 4);
    if (sub == 0) ac[grp][j - jblock] = p;
  }
  if (w == 0) {  // br . qv term (zero in this problem, kept for generality)
    const float* qrow = q + (size_t)bi * 512 + e0;
    float4 q0 = *(const float4*)qrow;
    float4 q1 = *(const float4*)(qrow + 4);
    float4 v0 = *(const float4*)(v + e0);
    float4 v1 = *(const float4*)(v + e0 + 4);
    float4 r0 = *(const float4*)(br + e0);
    float4 r1 = *(const float4*)(br + e0 + 4);
    float p = (q0.x + v0.x) * r0.x;
    p = fmaf(q0.y + v0.y, r0.y, p);
    p = fmaf(q0.z + v0.z, r0.z, p);
    p = fmaf(q0.w + v0.w, r0.w, p);
    p = fmaf(q1.x + v1.x, r1.x, p);
    p = fmaf(q1.y + v1.y, r1.y, p);
    p = fmaf(q1.z + v1.z, r1.z, p);
    p = fmaf(q1.w + v1.w, r1.w, p);
    p += __shfl_xor(p, 1);
    p += __shfl_xor(p, 2);
    p += __shfl_xor(p, 4);
    if (sub == 0) cterm[grp] = p;
  }
  __syncthreads();

  // g fragments in registers: gf[head][8]
  float gf[8][8];
#pragma unroll
  for (int n = 0; n < 8; ++n) {
    const float* grow = g + ((size_t)bi * 8 + n) * 512 + e0;
    float4 ga = *(const float4*)grow;
    float4 gb = *(const float4*)(grow + 4);
    gf[n][0] = ga.x; gf[n][1] = ga.y; gf[n][2] = ga.z; gf[n][3] = ga.w;
    gf[n][4] = gb.x; gf[n][5] = gb.y; gf[n][6] = gb.z; gf[n][7] = gb.w;
  }
  const int s1 = sub & 1, s2 = (sub >> 1) & 1, s4 = (sub >> 2) & 1;
  const float* rbase = rpe + (size_t)bi * 256 * 512;
#pragma unroll 2
  for (int jj = 0; jj < 32; ++jj) {
    int j = jbase + jj;
    const float* rrow = rbase + (size_t)j * 512 + e0;
    float4 r0 = *(const float4*)rrow;
    float4 r1 = *(const float4*)(rrow + 4);
    float a[8];
#pragma unroll
    for (int n = 0; n < 8; ++n) {
      float s = r0.x * gf[n][0];
      s = fmaf(r0.y, gf[n][1], s);
      s = fmaf(r0.z, gf[n][2], s);
      s = fmaf(r0.w, gf[n][3], s);
      s = fmaf(r1.x, gf[n][4], s);
      s = fmaf(r1.y, gf[n][5], s);
      s = fmaf(r1.z, gf[n][6], s);
      s = fmaf(r1.w, gf[n][7], s);
      a[n] = s;
    }
    // transpose-reduce: lane ends with head (lane&7)'s wave-wide sum
    float b0 = (s1 ? a[1] : a[0]) + __shfl_xor(s1 ? a[0] : a[1], 1);
    float b1 = (s1 ? a[3] : a[2]) + __shfl_xor(s1 ? a[2] : a[3], 1);
    float b2 = (s1 ? a[5] : a[4]) + __shfl_xor(s1 ? a[4] : a[5], 1);
    float b3 = (s1 ? a[7] : a[6]) + __shfl_xor(s1 ? a[6] : a[7], 1);
    float c0 = (s2 ? b1 : b0) + __shfl_xor(s2 ? b0 : b1, 2);
    float c1 = (s2 ? b3 : b2) + __shfl_xor(s2 ? b2 : b3, 2);
    float tot = (s4 ? c1 : c0) + __shfl_xor(s4 ? c0 : c1, 4);
    tot += __shfl_xor(tot, 8);
    tot += __shfl_xor(tot, 16);
    tot += __shfl_xor(tot, 32);
    if (lane < 8) {
      float val = (ac[lane][j - jblock] + cterm[lane] + tot) * 0.125f;
      if (j >= limit) val = -1e15f;
      scores[((size_t)(b * 8 + lane) * 256 + i) * 256 + j] = val;
    }
  }
}

// ---------------------------------------------------------------------------
// softmax over j + PV: ctx[b,i,n*64+d] = sum_j softmax(scores)[b,n,i,j]*val[b,j,n*64+d]
// one block per (b,i); wave handles 2 heads' softmax rows.
// ---------------------------------------------------------------------------
__global__ __launch_bounds__(256) void softmax_pv_k(const float* __restrict__ scores,
                                                    const float* __restrict__ val,
                                                    float* __restrict__ ctx) {
  const int bi = blockIdx.x;
  const int b = bi >> 8, i = bi & 255;
  const int t = threadIdx.x;
  const int lane = t & 63, w = t >> 6;
  __shared__ float p_lds[8][256];
#pragma unroll
  for (int h = 0; h < 2; ++h) {
    const int n = w * 2 + h;
    const float* srow = scores + ((size_t)(b * 8 + n) * 256 + i) * 256;
    float x0 = srow[lane], x1 = srow[lane + 64], x2 = srow[lane + 128], x3 = srow[lane + 192];
    float m = fmaxf(fmaxf(x0, x1), fmaxf(x2, x3));
#pragma unroll
    for (int off = 1; off < 64; off <<= 1) m = fmaxf(m, __shfl_xor(m, off));
    float e0 = __expf(x0 - m), e1 = __expf(x1 - m), e2 = __expf(x2 - m), e3 = __expf(x3 - m);
    float s = e0 + e1 + e2 + e3;
#pragma unroll
    for (int off = 1; off < 64; off <<= 1) s += __shfl_xor(s, off);
    float inv = 1.0f / s;
    p_lds[n][lane] = e0 * inv;
    p_lds[n][lane + 64] = e1 * inv;
    p_lds[n][lane + 128] = e2 * inv;
    p_lds[n][lane + 192] = e3 * inv;
  }
  __syncthreads();
  const int c = t * 2;
  const int n = c >> 6;
  float2 acc = {0.f, 0.f};
  const float* vb = val + (size_t)b * 256 * 512 + c;
#pragma unroll 4
  for (int j = 0; j < 256; ++j) {
    float p = p_lds[n][j];
    float2 vv = *(const float2*)(vb + (size_t)j * 512);
    acc.x = fmaf(p, vv.x, acc.x);
    acc.y = fmaf(p, vv.y, acc.y);
  }
  *(float2*)&ctx[(size_t)bi * 512 + c] = acc;
}

// ---------------------------------------------------------------------------
extern "C" void kernel_launch(void* const* d_in, const int* in_sizes, int n_in,
                              void* d_out, int out_size, void* d_ws, size_t ws_size,
                              hipStream_t stream) {
  const float* key     = (const float*)d_in[0];
  const float* query   = (const float*)d_in[1];
  const float* value   = (const float*)d_in[2];
  const int* seq_len   = (const int*)d_in[3];
  const int* lex_num   = (const int*)d_in[4];
  // d_in[5] pos_s, d_in[6] pos_e: unused by reference
  const float* rpe     = (const float*)d_in[7];
  const float* Wk      = (const float*)d_in[8];
  const float* bk      = (const float*)d_in[9];
  const float* Wq      = (const float*)d_in[10];
  const float* bq      = (const float*)d_in[11];
  const float* Wv      = (const float*)d_in[12];
  const float* bv      = (const float*)d_in[13];
  const float* Wr      = (const float*)d_in[14];
  const float* br      = (const float*)d_in[15];
  const float* u       = (const float*)d_in[16];
  const float* v       = (const float*)d_in[17];
  const float* Wf      = (const float*)d_in[18];
  const float* bf      = (const float*)d_in[19];
  float* out = (float*)d_out;

  float* ws     = (float*)d_ws;
  float* q_ws   = ws;                  // 262144
  float* k_ws   = q_ws + 262144;       // 262144
  float* val_ws = k_ws + 262144;       // 262144
  float* g_ws   = val_ws + 262144;     // 2097152
  float* sc_ws  = g_ws + 2097152;      // 1048576
  float* ctx_ws = sc_ws + 1048576;     // 262144  -> total 16 MB

  dim3 blk(256);
  // q/k/v projections (fused, grid z = 3)
  gemm512_k<<<dim3(8, 8, 3), blk, 0, stream>>>(query, Wq, bq, q_ws,
                                               key, Wk, bk, k_ws,
                                               value, Wv, bv, val_ws);
  // g = Wr_head @ (q + v_bias)
  g_gemm_k<<<dim3(8, 8, 8), blk, 0, stream>>>(q_ws, v, Wr, g_ws);
  // scores (streams the 256 MiB rpe exactly once)
  score_k<<<dim3(512, 2), blk, 0, stream>>>(q_ws, k_ws, g_ws, rpe, u, v, br,
                                            seq_len, lex_num, sc_ws);
  // softmax + PV
  softmax_pv_k<<<dim3(512), blk, 0, stream>>>(sc_ws, val_ws, ctx_ws);
  // final projection
  gemm512_k<<<dim3(8, 8, 1), blk, 0, stream>>>(ctx_ws, Wf, bf, out,
                                               ctx_ws, Wf, bf, out,
                                               ctx_ws, Wf, bf, out);
}

// Round 2
// 475.376 us; speedup vs baseline: 1.1157x; 1.1157x over previous
//
#include <hip/hip_runtime.h>
#include <math.h>

// Problem constants: B=2, L=256, H=512, NH=8, DH=64
// ws layout (floats): q[262144] k[262144] val[262144] g[2097152] ctx[262144]

// ---------------------------------------------------------------------------
// GEMM: C[512,512] = A[512,512] @ W[512,512] + bias[512]; grid z selects 1 of 3
// BM=BN=64, BK=16, 256 threads, 4x4 micro-tile, register-prefetch pipeline.
// ---------------------------------------------------------------------------
__global__ __launch_bounds__(256) void gemm512_k(
    const float* __restrict__ A0, const float* __restrict__ W0,
    const float* __restrict__ b0, float* __restrict__ C0,
    const float* __restrict__ A1, const float* __restrict__ W1,
    const float* __restrict__ b1, float* __restrict__ C1,
    const float* __restrict__ A2, const float* __restrict__ W2,
    const float* __restrict__ b2, float* __restrict__ C2) {
  const int z = blockIdx.z;
  const float* A    = (z == 0) ? A0 : (z == 1) ? A1 : A2;
  const float* W    = (z == 0) ? W0 : (z == 1) ? W1 : W2;
  const float* bias = (z == 0) ? b0 : (z == 1) ? b1 : b2;
  float* C          = (z == 0) ? C0 : (z == 1) ? C1 : C2;

  __shared__ float As[16][64];  // [k][m]
  __shared__ float Bs[16][64];  // [k][n]
  const int t  = threadIdx.x;
  const int tx = t & 15, ty = t >> 4;
  const int bm0 = blockIdx.y * 64, bn0 = blockIdx.x * 64;
  const int lm  = t >> 2;          // A-stage row 0..63
  const int lkq = (t & 3) << 2;    // A-stage k quad
  const int lk  = t >> 4;          // B-stage k 0..15
  const int lnq = (t & 15) << 2;   // B-stage n quad

  float acc[4][4] = {};
  float4 a4 = *(const float4*)&A[(bm0 + lm) * 512 + lkq];
  float4 b4 = *(const float4*)&W[lk * 512 + bn0 + lnq];
  for (int kt = 0; kt < 32; ++kt) {
    As[lkq + 0][lm] = a4.x;
    As[lkq + 1][lm] = a4.y;
    As[lkq + 2][lm] = a4.z;
    As[lkq + 3][lm] = a4.w;
    *(float4*)&Bs[lk][lnq] = b4;
    __syncthreads();
    float4 a4n = a4, b4n = b4;
    if (kt < 31) {  // issue next tile's loads before compute (hide latency)
      a4n = *(const float4*)&A[(bm0 + lm) * 512 + (kt + 1) * 16 + lkq];
      b4n = *(const float4*)&W[((kt + 1) * 16 + lk) * 512 + bn0 + lnq];
    }
#pragma unroll
    for (int k = 0; k < 16; ++k) {
      float4 av = *(const float4*)&As[k][ty * 4];
      float4 bv = *(const float4*)&Bs[k][tx * 4];
      acc[0][0] = fmaf(av.x, bv.x, acc[0][0]);
      acc[0][1] = fmaf(av.x, bv.y, acc[0][1]);
      acc[0][2] = fmaf(av.x, bv.z, acc[0][2]);
      acc[0][3] = fmaf(av.x, bv.w, acc[0][3]);
      acc[1][0] = fmaf(av.y, bv.x, acc[1][0]);
      acc[1][1] = fmaf(av.y, bv.y, acc[1][1]);
      acc[1][2] = fmaf(av.y, bv.z, acc[1][2]);
      acc[1][3] = fmaf(av.y, bv.w, acc[1][3]);
      acc[2][0] = fmaf(av.z, bv.x, acc[2][0]);
      acc[2][1] = fmaf(av.z, bv.y, acc[2][1]);
      acc[2][2] = fmaf(av.z, bv.z, acc[2][2]);
      acc[2][3] = fmaf(av.z, bv.w, acc[2][3]);
      acc[3][0] = fmaf(av.w, bv.x, acc[3][0]);
      acc[3][1] = fmaf(av.w, bv.y, acc[3][1]);
      acc[3][2] = fmaf(av.w, bv.z, acc[3][2]);
      acc[3][3] = fmaf(av.w, bv.w, acc[3][3]);
    }
    __syncthreads();
    a4 = a4n;
    b4 = b4n;
  }
  float4 bb = *(const float4*)&bias[bn0 + tx * 4];
#pragma unroll
  for (int r = 0; r < 4; ++r) {
    float4 o;
    o.x = acc[r][0] + bb.x;
    o.y = acc[r][1] + bb.y;
    o.z = acc[r][2] + bb.z;
    o.w = acc[r][3] + bb.w;
    *(float4*)&C[(size_t)(bm0 + ty * 4 + r) * 512 + bn0 + tx * 4] = o;
  }
}

// ---------------------------------------------------------------------------
// g[b,i,n,e] = sum_d Wr[e, n*64+d] * (q[b,i,n*64+d] + v[n,d])
// grid: (bi_tile=8, e_tile=8, n=8); K=64 fully staged.
// ---------------------------------------------------------------------------
__global__ __launch_bounds__(256) void g_gemm_k(const float* __restrict__ q,
                                                const float* __restrict__ vbias,
                                                const float* __restrict__ Wr,
                                                float* __restrict__ g) {
  __shared__ float As[64][64];  // [d][m]  qv
  __shared__ float Bs[64][64];  // [d][e]  Wr^T slice
  const int t   = threadIdx.x;
  const int bi0 = blockIdx.x * 64;
  const int eb  = blockIdx.y * 64;
  const int n   = blockIdx.z;
  const int row = t >> 2;        // 0..63
  const int dq  = (t & 3) << 4;  // 0,16,32,48
#pragma unroll
  for (int s = 0; s < 4; ++s) {
    int d = dq + s * 4;
    float4 a4 = *(const float4*)&q[(size_t)(bi0 + row) * 512 + n * 64 + d];
    float4 v4 = *(const float4*)&vbias[n * 64 + d];
    As[d + 0][row] = a4.x + v4.x;
    As[d + 1][row] = a4.y + v4.y;
    As[d + 2][row] = a4.z + v4.z;
    As[d + 3][row] = a4.w + v4.w;
    float4 b4 = *(const float4*)&Wr[(size_t)(eb + row) * 512 + n * 64 + d];
    Bs[d + 0][row] = b4.x;
    Bs[d + 1][row] = b4.y;
    Bs[d + 2][row] = b4.z;
    Bs[d + 3][row] = b4.w;
  }
  __syncthreads();
  const int tx = t & 15, ty = t >> 4;
  float acc[4][4] = {};
#pragma unroll 8
  for (int d = 0; d < 64; ++d) {
    float4 av = *(const float4*)&As[d][ty * 4];
    float4 bv = *(const float4*)&Bs[d][tx * 4];
    acc[0][0] = fmaf(av.x, bv.x, acc[0][0]);
    acc[0][1] = fmaf(av.x, bv.y, acc[0][1]);
    acc[0][2] = fmaf(av.x, bv.z, acc[0][2]);
    acc[0][3] = fmaf(av.x, bv.w, acc[0][3]);
    acc[1][0] = fmaf(av.y, bv.x, acc[1][0]);
    acc[1][1] = fmaf(av.y, bv.y, acc[1][1]);
    acc[1][2] = fmaf(av.y, bv.z, acc[1][2]);
    acc[1][3] = fmaf(av.y, bv.w, acc[1][3]);
    acc[2][0] = fmaf(av.z, bv.x, acc[2][0]);
    acc[2][1] = fmaf(av.z, bv.y, acc[2][1]);
    acc[2][2] = fmaf(av.z, bv.z, acc[2][2]);
    acc[2][3] = fmaf(av.z, bv.w, acc[2][3]);
    acc[3][0] = fmaf(av.w, bv.x, acc[3][0]);
    acc[3][1] = fmaf(av.w, bv.y, acc[3][1]);
    acc[3][2] = fmaf(av.w, bv.z, acc[3][2]);
    acc[3][3] = fmaf(av.w, bv.w, acc[3][3]);
  }
#pragma unroll
  for (int r = 0; r < 4; ++r) {
    float4 o = {acc[r][0], acc[r][1], acc[r][2], acc[r][3]};
    *(float4*)&g[((size_t)(bi0 + ty * 4 + r) * 8 + n) * 512 + eb + tx * 4] = o;
  }
}

// ---------------------------------------------------------------------------
// Fused scores + softmax + PV. One block per (b,i). Wave w owns j in
// [64w, 64w+64). Lane l owns e-slice [8l, 8l+8). Per j, the AC term
// (q+u).k is folded into the rpe.g partials before the wave-wide
// transpose-reduce, which yields (AC+BD)[head] for lanes 0..7.
// ---------------------------------------------------------------------------
__global__ __launch_bounds__(256) void attn_k(
    const float* __restrict__ q, const float* __restrict__ kk,
    const float* __restrict__ g, const float* __restrict__ rpe,
    const float* __restrict__ u, const float* __restrict__ v,
    const float* __restrict__ br, const int* __restrict__ seq_len,
    const int* __restrict__ lex_num, const float* __restrict__ val,
    float* __restrict__ ctx) {
  const int bi = blockIdx.x;
  const int b = bi >> 8;
  const int t = threadIdx.x;
  const int lane = t & 63, w = t >> 6;
  const int grp = lane >> 3, sub = lane & 7;
  const int e0 = lane << 3;
  __shared__ float sc[8][256];   // scores then probabilities
  __shared__ float cterm[8];     // br . (q+v) per head
  const int limit = seq_len[b] + lex_num[0];

  // per-lane (q+u) slice
  float qu[8];
  {
    const float* qrow = q + (size_t)bi * 512 + e0;
    float4 q0 = *(const float4*)qrow;
    float4 q1 = *(const float4*)(qrow + 4);
    float4 u0 = *(const float4*)(u + e0);
    float4 u1 = *(const float4*)(u + e0 + 4);
    qu[0] = q0.x + u0.x; qu[1] = q0.y + u0.y; qu[2] = q0.z + u0.z; qu[3] = q0.w + u0.w;
    qu[4] = q1.x + u1.x; qu[5] = q1.y + u1.y; qu[6] = q1.z + u1.z; qu[7] = q1.w + u1.w;
  }
  // g fragments in registers: gf[head][8]
  float gf[8][8];
#pragma unroll
  for (int n = 0; n < 8; ++n) {
    const float* grow = g + ((size_t)bi * 8 + n) * 512 + e0;
    float4 ga = *(const float4*)grow;
    float4 gb = *(const float4*)(grow + 4);
    gf[n][0] = ga.x; gf[n][1] = ga.y; gf[n][2] = ga.z; gf[n][3] = ga.w;
    gf[n][4] = gb.x; gf[n][5] = gb.y; gf[n][6] = gb.z; gf[n][7] = gb.w;
  }
  if (w == 0) {  // br . (q+v) per head (zero in this problem; kept for generality)
    const float* qrow = q + (size_t)bi * 512 + e0;
    float4 q0 = *(const float4*)qrow;
    float4 q1 = *(const float4*)(qrow + 4);
    float4 v0 = *(const float4*)(v + e0);
    float4 v1 = *(const float4*)(v + e0 + 4);
    float4 r0 = *(const float4*)(br + e0);
    float4 r1 = *(const float4*)(br + e0 + 4);
    float p = (q0.x + v0.x) * r0.x;
    p = fmaf(q0.y + v0.y, r0.y, p);
    p = fmaf(q0.z + v0.z, r0.z, p);
    p = fmaf(q0.w + v0.w, r0.w, p);
    p = fmaf(q1.x + v1.x, r1.x, p);
    p = fmaf(q1.y + v1.y, r1.y, p);
    p = fmaf(q1.z + v1.z, r1.z, p);
    p = fmaf(q1.w + v1.w, r1.w, p);
    p += __shfl_xor(p, 1);
    p += __shfl_xor(p, 2);
    p += __shfl_xor(p, 4);
    if (sub == 0) cterm[grp] = p;
  }
  __syncthreads();

  const int s1 = sub & 1, s2 = (sub >> 1) & 1, s4 = (sub >> 2) & 1;
  const float* rbase = rpe + (size_t)bi * 256 * 512;
  const float* kbase = kk + (size_t)b * 256 * 512;
#pragma unroll 2
  for (int jj = 0; jj < 64; ++jj) {
    const int j = w * 64 + jj;
    const float* rrow = rbase + (size_t)j * 512 + e0;
    const float* krow = kbase + (size_t)j * 512 + e0;
    float4 r0 = *(const float4*)rrow;
    float4 r1 = *(const float4*)(rrow + 4);
    float4 k0 = *(const float4*)krow;
    float4 k1 = *(const float4*)(krow + 4);
    // AC partial for this lane's head
    float kd = qu[0] * k0.x;
    kd = fmaf(qu[1], k0.y, kd);
    kd = fmaf(qu[2], k0.z, kd);
    kd = fmaf(qu[3], k0.w, kd);
    kd = fmaf(qu[4], k1.x, kd);
    kd = fmaf(qu[5], k1.y, kd);
    kd = fmaf(qu[6], k1.z, kd);
    kd = fmaf(qu[7], k1.w, kd);
    float a[8];
#pragma unroll
    for (int n = 0; n < 8; ++n) {
      float s = r0.x * gf[n][0];
      s = fmaf(r0.y, gf[n][1], s);
      s = fmaf(r0.z, gf[n][2], s);
      s = fmaf(r0.w, gf[n][3], s);
      s = fmaf(r1.x, gf[n][4], s);
      s = fmaf(r1.y, gf[n][5], s);
      s = fmaf(r1.z, gf[n][6], s);
      s = fmaf(r1.w, gf[n][7], s);
      a[n] = s + ((grp == n) ? kd : 0.0f);  // fold AC into head grp's slot
    }
    // transpose-reduce: lane ends with head (lane&7)'s wave-wide sum
    float b0 = (s1 ? a[1] : a[0]) + __shfl_xor(s1 ? a[0] : a[1], 1);
    float b1 = (s1 ? a[3] : a[2]) + __shfl_xor(s1 ? a[2] : a[3], 1);
    float b2 = (s1 ? a[5] : a[4]) + __shfl_xor(s1 ? a[4] : a[5], 1);
    float b3 = (s1 ? a[7] : a[6]) + __shfl_xor(s1 ? a[6] : a[7], 1);
    float c0 = (s2 ? b1 : b0) + __shfl_xor(s2 ? b0 : b1, 2);
    float c1 = (s2 ? b3 : b2) + __shfl_xor(s2 ? b2 : b3, 2);
    float tot = (s4 ? c1 : c0) + __shfl_xor(s4 ? c0 : c1, 4);
    tot += __shfl_xor(tot, 8);
    tot += __shfl_xor(tot, 16);
    tot += __shfl_xor(tot, 32);
    if (lane < 8) {
      float sval = (tot + cterm[lane]) * 0.125f;
      if (j >= limit) sval = -1e15f;
      sc[lane][j] = sval;
    }
  }
  __syncthreads();

  // softmax in-place: wave w handles heads 2w and 2w+1
#pragma unroll
  for (int h = 0; h < 2; ++h) {
    const int n = w * 2 + h;
    float x0 = sc[n][lane], x1 = sc[n][lane + 64];
    float x2 = sc[n][lane + 128], x3 = sc[n][lane + 192];
    float m = fmaxf(fmaxf(x0, x1), fmaxf(x2, x3));
#pragma unroll
    for (int off = 1; off < 64; off <<= 1) m = fmaxf(m, __shfl_xor(m, off));
    float e0v = __expf(x0 - m), e1v = __expf(x1 - m);
    float e2v = __expf(x2 - m), e3v = __expf(x3 - m);
    float s = e0v + e1v + e2v + e3v;
#pragma unroll
    for (int off = 1; off < 64; off <<= 1) s += __shfl_xor(s, off);
    float inv = 1.0f / s;
    sc[n][lane] = e0v * inv;
    sc[n][lane + 64] = e1v * inv;
    sc[n][lane + 128] = e2v * inv;
    sc[n][lane + 192] = e3v * inv;
  }
  __syncthreads();

  // PV: thread t owns channels [2t, 2t+2)
  const int c = t * 2;
  const int n = c >> 6;
  float2 acc = {0.f, 0.f};
  const float* vb = val + (size_t)b * 256 * 512 + c;
#pragma unroll 4
  for (int j = 0; j < 256; ++j) {
    float p = sc[n][j];
    float2 vv = *(const float2*)(vb + (size_t)j * 512);
    acc.x = fmaf(p, vv.x, acc.x);
    acc.y = fmaf(p, vv.y, acc.y);
  }
  float* crow = ctx + (size_t)bi * 512 + c;
  crow[0] = acc.x;
  crow[1] = acc.y;
}

// ---------------------------------------------------------------------------
extern "C" void kernel_launch(void* const* d_in, const int* in_sizes, int n_in,
                              void* d_out, int out_size, void* d_ws, size_t ws_size,
                              hipStream_t stream) {
  const float* key     = (const float*)d_in[0];
  const float* query   = (const float*)d_in[1];
  const float* value   = (const float*)d_in[2];
  const int* seq_len   = (const int*)d_in[3];
  const int* lex_num   = (const int*)d_in[4];
  // d_in[5] pos_s, d_in[6] pos_e: unused by reference
  const float* rpe     = (const float*)d_in[7];
  const float* Wk      = (const float*)d_in[8];
  const float* bk      = (const float*)d_in[9];
  const float* Wq      = (const float*)d_in[10];
  const float* bq      = (const float*)d_in[11];
  const float* Wv      = (const float*)d_in[12];
  const float* bv      = (const float*)d_in[13];
  const float* Wr      = (const float*)d_in[14];
  const float* br      = (const float*)d_in[15];
  const float* u       = (const float*)d_in[16];
  const float* v       = (const float*)d_in[17];
  const float* Wf      = (const float*)d_in[18];
  const float* bf      = (const float*)d_in[19];
  float* out = (float*)d_out;

  float* ws     = (float*)d_ws;
  float* q_ws   = ws;                  // 262144
  float* k_ws   = q_ws + 262144;       // 262144
  float* val_ws = k_ws + 262144;       // 262144
  float* g_ws   = val_ws + 262144;     // 2097152
  float* ctx_ws = g_ws + 2097152;      // 262144

  dim3 blk(256);
  // q/k/v projections (fused, grid z = 3)
  gemm512_k<<<dim3(8, 8, 3), blk, 0, stream>>>(query, Wq, bq, q_ws,
                                               key, Wk, bk, k_ws,
                                               value, Wv, bv, val_ws);
  // g = per-head Wr slice applied to (q + v_bias)
  g_gemm_k<<<dim3(8, 8, 8), blk, 0, stream>>>(q_ws, v, Wr, g_ws);
  // fused scores + softmax + PV (streams the 256 MiB rpe exactly once)
  attn_k<<<dim3(512), blk, 0, stream>>>(q_ws, k_ws, g_ws, rpe, u, v, br,
                                        seq_len, lex_num, val_ws, ctx_ws);
  // final projection
  gemm512_k<<<dim3(8, 8, 1), blk, 0, stream>>>(ctx_ws, Wf, bf, out,
                                               ctx_ws, Wf, bf, out,
                                               ctx_ws, Wf, bf, out);
}

// Round 3
// 454.002 us; speedup vs baseline: 1.1682x; 1.0471x over previous
//
#include <hip/hip_runtime.h>
#include <math.h>

// Problem constants: B=2, L=256, H=512, NH=8, DH=64
// ws layout (floats): q[262144] k[262144] val[262144] g[2097152] ctx[262144]

// ---------------------------------------------------------------------------
// GEMM: C[512,512] = A[512,512] @ W[512,512] + bias[512]; grid z selects 1 of 3
// BM=32, BN=64, BK=16, 128 threads (2 waves), 4x4 micro-tile, reg prefetch.
// Grid (8, 16, z): 384 blocks for qkv -> all 256 CUs covered.
// ---------------------------------------------------------------------------
__global__ __launch_bounds__(128) void gemm512_k(
    const float* __restrict__ A0, const float* __restrict__ W0,
    const float* __restrict__ b0, float* __restrict__ C0,
    const float* __restrict__ A1, const float* __restrict__ W1,
    const float* __restrict__ b1, float* __restrict__ C1,
    const float* __restrict__ A2, const float* __restrict__ W2,
    const float* __restrict__ b2, float* __restrict__ C2) {
  const int z = blockIdx.z;
  const float* A    = (z == 0) ? A0 : (z == 1) ? A1 : A2;
  const float* W    = (z == 0) ? W0 : (z == 1) ? W1 : W2;
  const float* bias = (z == 0) ? b0 : (z == 1) ? b1 : b2;
  float* C          = (z == 0) ? C0 : (z == 1) ? C1 : C2;

  __shared__ float As[16][32];  // [k][m]
  __shared__ float Bs[16][64];  // [k][n]
  const int t  = threadIdx.x;            // 0..127
  const int tx = t & 15, ty = t >> 4;    // tx: n-quad 0..15, ty: m-quad 0..7
  const int bm0 = blockIdx.y * 32, bn0 = blockIdx.x * 64;
  const int arow = t >> 2;               // 0..31 (A-stage m)
  const int akq  = (t & 3) << 2;         // A-stage k quad
  const int bk   = t >> 4;               // 0..7 (B-stage k; also k+8)
  const int bnq  = (t & 15) << 2;        // B-stage n quad

  float acc[4][4] = {};
  float4 a4 = *(const float4*)&A[(bm0 + arow) * 512 + akq];
  float4 w0 = *(const float4*)&W[bk * 512 + bn0 + bnq];
  float4 w1 = *(const float4*)&W[(bk + 8) * 512 + bn0 + bnq];
  for (int kt = 0; kt < 32; ++kt) {
    As[akq + 0][arow] = a4.x;
    As[akq + 1][arow] = a4.y;
    As[akq + 2][arow] = a4.z;
    As[akq + 3][arow] = a4.w;
    *(float4*)&Bs[bk][bnq] = w0;
    *(float4*)&Bs[bk + 8][bnq] = w1;
    __syncthreads();
    if (kt < 31) {  // prefetch next tile into registers (hide latency)
      a4 = *(const float4*)&A[(bm0 + arow) * 512 + (kt + 1) * 16 + akq];
      w0 = *(const float4*)&W[((kt + 1) * 16 + bk) * 512 + bn0 + bnq];
      w1 = *(const float4*)&W[((kt + 1) * 16 + bk + 8) * 512 + bn0 + bnq];
    }
#pragma unroll
    for (int k = 0; k < 16; ++k) {
      float4 av = *(const float4*)&As[k][ty * 4];
      float4 bv = *(const float4*)&Bs[k][tx * 4];
      acc[0][0] = fmaf(av.x, bv.x, acc[0][0]);
      acc[0][1] = fmaf(av.x, bv.y, acc[0][1]);
      acc[0][2] = fmaf(av.x, bv.z, acc[0][2]);
      acc[0][3] = fmaf(av.x, bv.w, acc[0][3]);
      acc[1][0] = fmaf(av.y, bv.x, acc[1][0]);
      acc[1][1] = fmaf(av.y, bv.y, acc[1][1]);
      acc[1][2] = fmaf(av.y, bv.z, acc[1][2]);
      acc[1][3] = fmaf(av.y, bv.w, acc[1][3]);
      acc[2][0] = fmaf(av.z, bv.x, acc[2][0]);
      acc[2][1] = fmaf(av.z, bv.y, acc[2][1]);
      acc[2][2] = fmaf(av.z, bv.z, acc[2][2]);
      acc[2][3] = fmaf(av.z, bv.w, acc[2][3]);
      acc[3][0] = fmaf(av.w, bv.x, acc[3][0]);
      acc[3][1] = fmaf(av.w, bv.y, acc[3][1]);
      acc[3][2] = fmaf(av.w, bv.z, acc[3][2]);
      acc[3][3] = fmaf(av.w, bv.w, acc[3][3]);
    }
    __syncthreads();
  }
  float4 bb = *(const float4*)&bias[bn0 + tx * 4];
#pragma unroll
  for (int r = 0; r < 4; ++r) {
    float4 o;
    o.x = acc[r][0] + bb.x;
    o.y = acc[r][1] + bb.y;
    o.z = acc[r][2] + bb.z;
    o.w = acc[r][3] + bb.w;
    *(float4*)&C[(size_t)(bm0 + ty * 4 + r) * 512 + bn0 + tx * 4] = o;
  }
}

// ---------------------------------------------------------------------------
// g[b,i,n,e] = sum_d Wr[e, n*64+d] * (q[b,i,n*64+d] + v[n,d])
// grid: (bi_tile=8, e_tile=8, n=8); K=64 fully staged.
// ---------------------------------------------------------------------------
__global__ __launch_bounds__(256) void g_gemm_k(const float* __restrict__ q,
                                                const float* __restrict__ vbias,
                                                const float* __restrict__ Wr,
                                                float* __restrict__ g) {
  __shared__ float As[64][64];  // [d][m]  qv
  __shared__ float Bs[64][64];  // [d][e]  Wr^T slice
  const int t   = threadIdx.x;
  const int bi0 = blockIdx.x * 64;
  const int eb  = blockIdx.y * 64;
  const int n   = blockIdx.z;
  const int row = t >> 2;        // 0..63
  const int dq  = (t & 3) << 4;  // 0,16,32,48
#pragma unroll
  for (int s = 0; s < 4; ++s) {
    int d = dq + s * 4;
    float4 a4 = *(const float4*)&q[(size_t)(bi0 + row) * 512 + n * 64 + d];
    float4 v4 = *(const float4*)&vbias[n * 64 + d];
    As[d + 0][row] = a4.x + v4.x;
    As[d + 1][row] = a4.y + v4.y;
    As[d + 2][row] = a4.z + v4.z;
    As[d + 3][row] = a4.w + v4.w;
    float4 b4 = *(const float4*)&Wr[(size_t)(eb + row) * 512 + n * 64 + d];
    Bs[d + 0][row] = b4.x;
    Bs[d + 1][row] = b4.y;
    Bs[d + 2][row] = b4.z;
    Bs[d + 3][row] = b4.w;
  }
  __syncthreads();
  const int tx = t & 15, ty = t >> 4;
  float acc[4][4] = {};
#pragma unroll 8
  for (int d = 0; d < 64; ++d) {
    float4 av = *(const float4*)&As[d][ty * 4];
    float4 bv = *(const float4*)&Bs[d][tx * 4];
    acc[0][0] = fmaf(av.x, bv.x, acc[0][0]);
    acc[0][1] = fmaf(av.x, bv.y, acc[0][1]);
    acc[0][2] = fmaf(av.x, bv.z, acc[0][2]);
    acc[0][3] = fmaf(av.x, bv.w, acc[0][3]);
    acc[1][0] = fmaf(av.y, bv.x, acc[1][0]);
    acc[1][1] = fmaf(av.y, bv.y, acc[1][1]);
    acc[1][2] = fmaf(av.y, bv.z, acc[1][2]);
    acc[1][3] = fmaf(av.y, bv.w, acc[1][3]);
    acc[2][0] = fmaf(av.z, bv.x, acc[2][0]);
    acc[2][1] = fmaf(av.z, bv.y, acc[2][1]);
    acc[2][2] = fmaf(av.z, bv.z, acc[2][2]);
    acc[2][3] = fmaf(av.z, bv.w, acc[2][3]);
    acc[3][0] = fmaf(av.w, bv.x, acc[3][0]);
    acc[3][1] = fmaf(av.w, bv.y, acc[3][1]);
    acc[3][2] = fmaf(av.w, bv.z, acc[3][2]);
    acc[3][3] = fmaf(av.w, bv.w, acc[3][3]);
  }
#pragma unroll
  for (int r = 0; r < 4; ++r) {
    float4 o = {acc[r][0], acc[r][1], acc[r][2], acc[r][3]};
    *(float4*)&g[((size_t)(bi0 + ty * 4 + r) * 8 + n) * 512 + eb + tx * 4] = o;
  }
}

// ---------------------------------------------------------------------------
// Fused scores + softmax + PV. One block of 512 threads per (b,i).
// Wave w (0..7) owns j in [32w, 32w+32). Lane l owns e-slice [8l, 8l+8).
// j >= seq_len[b]+lex_num are skipped entirely (score = -1e15, prob = 0):
// saves ~25% of the 256 MiB rpe stream on average.
// ---------------------------------------------------------------------------
__global__ __launch_bounds__(512, 4) void attn_k(
    const float* __restrict__ q, const float* __restrict__ kk,
    const float* __restrict__ g, const float* __restrict__ rpe,
    const float* __restrict__ u, const float* __restrict__ v,
    const float* __restrict__ br, const int* __restrict__ seq_len,
    const int* __restrict__ lex_num, const float* __restrict__ val,
    float* __restrict__ ctx) {
  const int bi = blockIdx.x;
  const int b = bi >> 8;
  const int t = threadIdx.x;
  const int lane = t & 63, w = t >> 6;   // 8 waves
  const int grp = lane >> 3, sub = lane & 7;
  const int e0 = lane << 3;
  __shared__ float sc[8][256];   // scores then probabilities
  __shared__ float cterm[8];     // br . (q+v) per head
  const int limit = seq_len[b] + lex_num[0];   // 128..256

  // per-lane (q+u) slice
  float qu[8];
  {
    const float* qrow = q + (size_t)bi * 512 + e0;
    float4 q0 = *(const float4*)qrow;
    float4 q1 = *(const float4*)(qrow + 4);
    float4 u0 = *(const float4*)(u + e0);
    float4 u1 = *(const float4*)(u + e0 + 4);
    qu[0] = q0.x + u0.x; qu[1] = q0.y + u0.y; qu[2] = q0.z + u0.z; qu[3] = q0.w + u0.w;
    qu[4] = q1.x + u1.x; qu[5] = q1.y + u1.y; qu[6] = q1.z + u1.z; qu[7] = q1.w + u1.w;
  }
  // g fragments in registers: gf[head][8]
  float gf[8][8];
#pragma unroll
  for (int n = 0; n < 8; ++n) {
    const float* grow = g + ((size_t)bi * 8 + n) * 512 + e0;
    float4 ga = *(const float4*)grow;
    float4 gb = *(const float4*)(grow + 4);
    gf[n][0] = ga.x; gf[n][1] = ga.y; gf[n][2] = ga.z; gf[n][3] = ga.w;
    gf[n][4] = gb.x; gf[n][5] = gb.y; gf[n][6] = gb.z; gf[n][7] = gb.w;
  }
  if (w == 0) {  // br . (q+v) per head (zero here; kept for generality)
    const float* qrow = q + (size_t)bi * 512 + e0;
    float4 q0 = *(const float4*)qrow;
    float4 q1 = *(const float4*)(qrow + 4);
    float4 v0 = *(const float4*)(v + e0);
    float4 v1 = *(const float4*)(v + e0 + 4);
    float4 r0 = *(const float4*)(br + e0);
    float4 r1 = *(const float4*)(br + e0 + 4);
    float p = (q0.x + v0.x) * r0.x;
    p = fmaf(q0.y + v0.y, r0.y, p);
    p = fmaf(q0.z + v0.z, r0.z, p);
    p = fmaf(q0.w + v0.w, r0.w, p);
    p = fmaf(q1.x + v1.x, r1.x, p);
    p = fmaf(q1.y + v1.y, r1.y, p);
    p = fmaf(q1.z + v1.z, r1.z, p);
    p = fmaf(q1.w + v1.w, r1.w, p);
    p += __shfl_xor(p, 1);
    p += __shfl_xor(p, 2);
    p += __shfl_xor(p, 4);
    if (sub == 0) cterm[grp] = p;
  }
  __syncthreads();
  const float ct = (lane < 8) ? cterm[lane] : 0.0f;

  const int jbase = w * 32;
  int jend = limit - jbase;
  jend = jend < 0 ? 0 : (jend > 32 ? 32 : jend);
  // masked tail: scores are the constant -1e15, no memory needed
  if (lane < 8) {
    for (int jj = jend; jj < 32; ++jj) sc[lane][jbase + jj] = -1e15f;
  }

  const int s1 = sub & 1, s2 = (sub >> 1) & 1, s4 = (sub >> 2) & 1;
  const float* rbase = rpe + (size_t)bi * 256 * 512;
  const float* kbase = kk + (size_t)b * 256 * 512;
#pragma unroll 2
  for (int jj = 0; jj < jend; ++jj) {
    const int j = jbase + jj;
    const float* rrow = rbase + (size_t)j * 512 + e0;
    const float* krow = kbase + (size_t)j * 512 + e0;
    float4 r0 = *(const float4*)rrow;
    float4 r1 = *(const float4*)(rrow + 4);
    float4 k0 = *(const float4*)krow;
    float4 k1 = *(const float4*)(krow + 4);
    // AC partial for this lane's head
    float kd = qu[0] * k0.x;
    kd = fmaf(qu[1], k0.y, kd);
    kd = fmaf(qu[2], k0.z, kd);
    kd = fmaf(qu[3], k0.w, kd);
    kd = fmaf(qu[4], k1.x, kd);
    kd = fmaf(qu[5], k1.y, kd);
    kd = fmaf(qu[6], k1.z, kd);
    kd = fmaf(qu[7], k1.w, kd);
    float a[8];
#pragma unroll
    for (int n = 0; n < 8; ++n) {
      float s = r0.x * gf[n][0];
      s = fmaf(r0.y, gf[n][1], s);
      s = fmaf(r0.z, gf[n][2], s);
      s = fmaf(r0.w, gf[n][3], s);
      s = fmaf(r1.x, gf[n][4], s);
      s = fmaf(r1.y, gf[n][5], s);
      s = fmaf(r1.z, gf[n][6], s);
      s = fmaf(r1.w, gf[n][7], s);
      a[n] = s + ((grp == n) ? kd : 0.0f);  // fold AC into head grp's slot
    }
    // transpose-reduce: lane ends with head (lane&7)'s wave-wide sum
    float b0 = (s1 ? a[1] : a[0]) + __shfl_xor(s1 ? a[0] : a[1], 1);
    float b1 = (s1 ? a[3] : a[2]) + __shfl_xor(s1 ? a[2] : a[3], 1);
    float b2 = (s1 ? a[5] : a[4]) + __shfl_xor(s1 ? a[4] : a[5], 1);
    float b3 = (s1 ? a[7] : a[6]) + __shfl_xor(s1 ? a[6] : a[7], 1);
    float c0 = (s2 ? b1 : b0) + __shfl_xor(s2 ? b0 : b1, 2);
    float c1 = (s2 ? b3 : b2) + __shfl_xor(s2 ? b2 : b3, 2);
    float tot = (s4 ? c1 : c0) + __shfl_xor(s4 ? c0 : c1, 4);
    tot += __shfl_xor(tot, 8);
    tot += __shfl_xor(tot, 16);
    tot += __shfl_xor(tot, 32);
    if (lane < 8) sc[lane][j] = (tot + ct) * 0.125f;
  }
  __syncthreads();

  // softmax in-place: wave w handles head w
  {
    const int n = w;
    float x0 = sc[n][lane], x1 = sc[n][lane + 64];
    float x2 = sc[n][lane + 128], x3 = sc[n][lane + 192];
    float m = fmaxf(fmaxf(x0, x1), fmaxf(x2, x3));
#pragma unroll
    for (int off = 1; off < 64; off <<= 1) m = fmaxf(m, __shfl_xor(m, off));
    float e0v = __expf(x0 - m), e1v = __expf(x1 - m);
    float e2v = __expf(x2 - m), e3v = __expf(x3 - m);
    float s = e0v + e1v + e2v + e3v;
#pragma unroll
    for (int off = 1; off < 64; off <<= 1) s += __shfl_xor(s, off);
    float inv = 1.0f / s;
    sc[n][lane] = e0v * inv;
    sc[n][lane + 64] = e1v * inv;
    sc[n][lane + 128] = e2v * inv;
    sc[n][lane + 192] = e3v * inv;
  }
  __syncthreads();

  // PV: thread t owns channel c = t; probs are 0 for j >= limit -> bound loop
  const int c = t;
  const int n = t >> 6;
  float acc = 0.0f;
  const float* vb = val + (size_t)b * 256 * 512 + c;
#pragma unroll 4
  for (int j = 0; j < limit; ++j) {
    acc = fmaf(sc[n][j], vb[(size_t)j * 512], acc);
  }
  ctx[(size_t)bi * 512 + c] = acc;
}

// ---------------------------------------------------------------------------
extern "C" void kernel_launch(void* const* d_in, const int* in_sizes, int n_in,
                              void* d_out, int out_size, void* d_ws, size_t ws_size,
                              hipStream_t stream) {
  const float* key     = (const float*)d_in[0];
  const float* query   = (const float*)d_in[1];
  const float* value   = (const float*)d_in[2];
  const int* seq_len   = (const int*)d_in[3];
  const int* lex_num   = (const int*)d_in[4];
  // d_in[5] pos_s, d_in[6] pos_e: unused by reference
  const float* rpe     = (const float*)d_in[7];
  const float* Wk      = (const float*)d_in[8];
  const float* bk      = (const float*)d_in[9];
  const float* Wq      = (const float*)d_in[10];
  const float* bq      = (const float*)d_in[11];
  const float* Wv      = (const float*)d_in[12];
  const float* bv      = (const float*)d_in[13];
  const float* Wr      = (const float*)d_in[14];
  const float* br      = (const float*)d_in[15];
  const float* u       = (const float*)d_in[16];
  const float* v       = (const float*)d_in[17];
  const float* Wf      = (const float*)d_in[18];
  const float* bf      = (const float*)d_in[19];
  float* out = (float*)d_out;

  float* ws     = (float*)d_ws;
  float* q_ws   = ws;                  // 262144
  float* k_ws   = q_ws + 262144;       // 262144
  float* val_ws = k_ws + 262144;       // 262144
  float* g_ws   = val_ws + 262144;     // 2097152
  float* ctx_ws = g_ws + 2097152;      // 262144

  // q/k/v projections (fused, grid z = 3; 384 blocks cover all CUs)
  gemm512_k<<<dim3(8, 16, 3), dim3(128), 0, stream>>>(query, Wq, bq, q_ws,
                                                      key, Wk, bk, k_ws,
                                                      value, Wv, bv, val_ws);
  // g = per-head Wr slice applied to (q + v_bias)
  g_gemm_k<<<dim3(8, 8, 8), dim3(256), 0, stream>>>(q_ws, v, Wr, g_ws);
  // fused scores + softmax + PV (streams masked rpe exactly once)
  attn_k<<<dim3(512), dim3(512), 0, stream>>>(q_ws, k_ws, g_ws, rpe, u, v, br,
                                              seq_len, lex_num, val_ws, ctx_ws);
  // final projection
  gemm512_k<<<dim3(8, 16, 1), dim3(128), 0, stream>>>(ctx_ws, Wf, bf, out,
                                                      ctx_ws, Wf, bf, out,
                                                      ctx_ws, Wf, bf, out);
}